// Round 1
// 300.715 us; speedup vs baseline: 1.0031x; 1.0031x over previous
//
#include <hip/hip_runtime.h>
#include <hip/hip_bf16.h>

// KGAT-style 2-hop relational graph attention on MI355X — round 8.
//
// vs round 7 (301.6 us; hops 2x77.5 us, VALUBusy ~61%, HBM 21%):
//  1. Degree-grouped schedule: counting sort of heads by clamped degree
//     (33 bins). A wave's 4 groups now process equal-length segments, so the
//     inner trip count drops from E[max of 4 Poisson(6)] ~= 9.5 to ~6.1
//     (-36% predicated issue waste). len is packed into the order word
//     (n | len<<18), deleting the dependent cnt[n] load per segment.
//     Bit-identical numerics (per-head work and in-segment order unchanged).
//  2. cursor memset + hist zeroing folded into prep (one fewer dispatch).
//
// dtypes: all float32 (reference), indices int32 (harness int64->int32).

#define N_ENT  200000
#define N_EDGE 1200000
#define N_REL  32
#define DIM    64
#define LEAKY  0.2f
#define CAP    32                                      // bucket slots per head
#define NCOLOR 16
#define BAND (N_ENT / NCOLOR)                          // 12500 heads per color
#define NSLICE ((N_EDGE / 4 + 255) / 256)              // 1172 blocks per color
#define NBIN   (CAP + 1)                               // degree bins 0..32

template <int CTRL>
__device__ __forceinline__ float dpp_add(float x) {
  int t = __builtin_amdgcn_update_dpp(0, __float_as_int(x), CTRL, 0xF, 0xF, true);
  return x + __int_as_float(t);
}
// 16-lane (DPP row) allreduce sum; result valid in all 16 lanes of the row.
__device__ __forceinline__ float red16(float x) {
  x = dpp_add<0xB1>(x);    // quad_perm [1,0,3,2]  (xor 1)
  x = dpp_add<0x4E>(x);    // quad_perm [2,3,0,1]  (xor 2)
  x = dpp_add<0x124>(x);   // row_ror:4
  x = dpp_add<0x128>(x);   // row_ror:8
  return x;
}

// 4 bf16 (as 2 uints, low/high packed) -> float4
__device__ __forceinline__ float4 unpack4(uint2 u) {
  float4 t;
  t.x = __uint_as_float(u.x << 16);
  t.y = __uint_as_float(u.x & 0xFFFF0000u);
  t.z = __uint_as_float(u.y << 16);
  t.w = __uint_as_float(u.y & 0xFFFF0000u);
  return t;
}
// two f32 -> packed bf16 pair (round-to-nearest-even)
__device__ __forceinline__ unsigned pk(float a, float b) {
  unsigned ua = __float_as_uint(a);
  ua += 0x7FFFu + ((ua >> 16) & 1u);
  unsigned ub = __float_as_uint(b);
  ub += 0x7FFFu + ((ub >> 16) & 1u);
  return (ua >> 16) | (ub & 0xFFFF0000u);
}

// prep: build Q (Q[r*128+k] = W[k,:] . R[r,:]) + convert ent0 -> bf16 table
//       + zero cursor and degree histogram (replaces memsetAsync)
__global__ void prep(const float* __restrict__ W, const float* __restrict__ R,
                     float* __restrict__ Q,
                     const float4* __restrict__ ent04,
                     uint2* __restrict__ ent0b,
                     int* __restrict__ cursor,
                     int* __restrict__ hist) {
  int i = blockIdx.x * blockDim.x + threadIdx.x;
  if (i < N_REL * 2 * DIM) {
    int r = i >> 7;
    int k = i & 127;
    float acc = 0.f;
#pragma unroll 8
    for (int j = 0; j < DIM; ++j)
      acc += W[k * DIM + j] * R[r * DIM + j];
    Q[i] = acc;
  }
  if (i < N_ENT) cursor[i] = 0;
  if (i < NBIN) hist[i] = 0;
  if (i < N_ENT * DIM / 4) {
    float4 v = ent04[i];
    ent0b[i] = make_uint2(pk(v.x, v.y), pk(v.z, v.w));
  }
}

// bucket[h*CAP + slot] = tail | (type << 18); 4 edges/thread, 16 color phases
// by head band (band bucket region = 1.6 MB -> L2-resident during its phase).
__global__ void fill_bucket(const int4* __restrict__ head4,
                            const int4* __restrict__ tail4,
                            const int4* __restrict__ type4,
                            int* __restrict__ cursor,
                            unsigned* __restrict__ bucket) {
  int color = blockIdx.x / NSLICE;
  int slice = blockIdx.x - color * NSLICE;
  int i = slice * blockDim.x + threadIdx.x;
  if (i >= N_EDGE / 4) return;
  int4 h = head4[i];
  int lo = color * BAND, hi = lo + BAND;
  bool mx = (h.x >= lo) & (h.x < hi);
  bool my = (h.y >= lo) & (h.y < hi);
  bool mz = (h.z >= lo) & (h.z < hi);
  bool mw = (h.w >= lo) & (h.w < hi);
  if (!(mx | my | mz | mw)) return;
  int4 t = tail4[i];
  int4 r = type4[i];
  int p;
  if (mx) { p = atomicAdd(&cursor[h.x], 1);
            if (p < CAP) bucket[h.x * CAP + p] = (unsigned)t.x | ((unsigned)r.x << 18); }
  if (my) { p = atomicAdd(&cursor[h.y], 1);
            if (p < CAP) bucket[h.y * CAP + p] = (unsigned)t.y | ((unsigned)r.y << 18); }
  if (mz) { p = atomicAdd(&cursor[h.z], 1);
            if (p < CAP) bucket[h.z * CAP + p] = (unsigned)t.z | ((unsigned)r.z << 18); }
  if (mw) { p = atomicAdd(&cursor[h.w], 1);
            if (p < CAP) bucket[h.w * CAP + p] = (unsigned)t.w | ((unsigned)r.w << 18); }
}

// ---- counting sort of heads by clamped degree (33 bins) ----
__global__ void hist_deg(const int* __restrict__ cnt, int* __restrict__ hist) {
  __shared__ int lh[NBIN];
  if (threadIdx.x < NBIN) lh[threadIdx.x] = 0;
  __syncthreads();
  int i = blockIdx.x * blockDim.x + threadIdx.x;
  if (i < N_ENT) atomicAdd(&lh[min(cnt[i], CAP)], 1);
  __syncthreads();
  if (threadIdx.x < NBIN) atomicAdd(&hist[threadIdx.x], lh[threadIdx.x]);
}

__global__ void scan_deg(const int* __restrict__ hist, int* __restrict__ binCur) {
  if (threadIdx.x == 0) {
    int s = 0;
    for (int b = 0; b < NBIN; ++b) { binCur[b] = s; s += hist[b]; }
  }
}

// order[pos] = n | (len << 18); heads grouped by degree -> equal trip counts
// for the 4 groups of a wave. Block-aggregated scatter: LDS atomics give the
// in-block rank, one global atomicAdd per (block, bin) claims the base.
__global__ void scatter_deg(const int* __restrict__ cnt,
                            int* __restrict__ binCur,
                            unsigned* __restrict__ order) {
  __shared__ int lh[NBIN];
  __shared__ int lbase[NBIN];
  if (threadIdx.x < NBIN) lh[threadIdx.x] = 0;
  __syncthreads();
  int i = blockIdx.x * blockDim.x + threadIdx.x;
  int d = 0, rank = 0;
  bool valid = (i < N_ENT);
  if (valid) {
    d = min(cnt[i], CAP);
    rank = atomicAdd(&lh[d], 1);
  }
  __syncthreads();
  if (threadIdx.x < NBIN)
    lbase[threadIdx.x] = atomicAdd(&binCur[threadIdx.x], lh[threadIdx.x]);
  __syncthreads();
  if (valid)
    order[lbase[d] + rank] = (unsigned)i | ((unsigned)d << 18);
}

// persistent hop kernel: wave = 4 groups x 16 lanes, 4 heads/wave, heads taken
// from the degree-sorted order[] (len packed in bits 18..23 -> no cnt load).
// Gathers are bf16 rows (128 B = 1 line). Softmax un-maxed (logits << 88).
// HOP==1: heads = ent0 (f32), gather = ent0b, out = h1b (bf16)
// HOP==2: heads = h1b, gather = h1b, out = 0.25*ent0 + 0.5*eh + h2 (f32)
template <int HOP>
__global__ __launch_bounds__(256, 8) void hop_kernel(
    const float* __restrict__ ent0,
    const ushort* __restrict__ entb,     // bf16 gather table
    const float4* __restrict__ Qg,
    const unsigned* __restrict__ order,
    const unsigned* __restrict__ bucket,
    uint2* __restrict__ outb,            // HOP1
    float* __restrict__ outf) {          // HOP2
  __shared__ float4 sQ[N_REL * 32];   // [r][half(2)][sub(16)]
  for (int i = threadIdx.x; i < N_REL * 32; i += blockDim.x) sQ[i] = Qg[i];
  __syncthreads();
  const int lane = threadIdx.x & 63;
  const int sub = lane & 15;
  const int grp = lane >> 4;
  const int wave = (blockIdx.x * blockDim.x + threadIdx.x) >> 6;
  const int nWaves = (gridDim.x * blockDim.x) >> 6;
  const uint2* gtab = (const uint2*)entb;
  for (int n4 = wave * 4; n4 < N_ENT; n4 += nWaves * 4) {
    unsigned oe = order[n4 + grp];    // N_ENT % 4 == 0 -> always < N_ENT
    int n = (int)(oe & 0x3FFFFu);
    int len = (int)(oe >> 18);
    float4 eh;
    if (HOP == 1)
      eh = ((const float4*)(ent0 + (size_t)n * DIM))[sub];
    else
      eh = unpack4(gtab[(size_t)n * 16 + sub]);
    int b = n * CAP;
    float l = 0.f;
    float4 acc = make_float4(0.f, 0.f, 0.f, 0.f);
    // depth-2 software pipeline over the segment (predicated per group)
    unsigned p0 = 0u, p1 = 0u;
    uint2 t0 = make_uint2(0u, 0u), t1 = t0;
    if (0 < len) { p0 = bucket[b];     t0 = gtab[(size_t)(p0 & 0x3FFFFu) * 16 + sub]; }
    if (1 < len) { p1 = bucket[b + 1]; t1 = gtab[(size_t)(p1 & 0x3FFFFu) * 16 + sub]; }
    for (int i = 0; __any(i < len); ++i) {
      unsigned p2 = 0u;
      uint2 t2 = make_uint2(0u, 0u);
      if (i + 2 < len) { p2 = bucket[b + i + 2];
                         t2 = gtab[(size_t)(p2 & 0x3FFFFu) * 16 + sub]; }
      if (i < len) {
        int r = (int)(p0 >> 18);
        float4 qh = sQ[r * 32 + sub];
        float4 qt = sQ[r * 32 + 16 + sub];
        float4 et = unpack4(t0);
        float d = eh.x * qh.x + eh.y * qh.y + eh.z * qh.z + eh.w * qh.w
                + et.x * qt.x + et.y * qt.y + et.z * qt.z + et.w * qt.w;
        d = red16(d);
        float v = d > 0.f ? d : LEAKY * d;
        float ex = __expf(v);
        l += ex;
        acc.x = fmaf(ex, et.x, acc.x);
        acc.y = fmaf(ex, et.y, acc.y);
        acc.z = fmaf(ex, et.z, acc.z);
        acc.w = fmaf(ex, et.w, acc.w);
      }
      p0 = p1; t0 = t1; p1 = p2; t1 = t2;
    }
    float inv = (l > 0.f) ? 1.f / l : 0.f;
    float4 v;
    v.x = fmaf(acc.x, inv, eh.x);
    v.y = fmaf(acc.y, inv, eh.y);
    v.z = fmaf(acc.z, inv, eh.z);
    v.w = fmaf(acc.w, inv, eh.w);
    float s = v.x * v.x + v.y * v.y + v.z * v.z + v.w * v.w;
    s = red16(s);
    float rn = 1.f / fmaxf(sqrtf(s), 1e-12f);
    if (HOP == 1) {
      outb[(size_t)n * 16 + sub] = make_uint2(pk(v.x * rn, v.y * rn),
                                              pk(v.z * rn, v.w * rn));
    } else {
      float4 e0 = ((const float4*)(ent0 + (size_t)n * DIM))[sub];
      float4 o;
      o.x = fmaf(0.25f, e0.x, fmaf(0.5f, eh.x, v.x * rn));
      o.y = fmaf(0.25f, e0.y, fmaf(0.5f, eh.y, v.y * rn));
      o.z = fmaf(0.25f, e0.z, fmaf(0.5f, eh.z, v.z * rn));
      o.w = fmaf(0.25f, e0.w, fmaf(0.5f, eh.w, v.w * rn));
      ((float4*)(outf + (size_t)n * DIM))[sub] = o;
    }
  }
}

extern "C" void kernel_launch(void* const* d_in, const int* in_sizes, int n_in,
                              void* d_out, int out_size, void* d_ws, size_t ws_size,
                              hipStream_t stream) {
  const float* ent0 = (const float*)d_in[0];
  const float* rel  = (const float*)d_in[1];
  const float* W    = (const float*)d_in[2];
  const int* edge_index = (const int*)d_in[3];
  const int* etype      = (const int*)d_in[4];
  const int* head = edge_index;            // edge_index[0, :]
  const int* tail = edge_index + N_EDGE;   // edge_index[1, :]
  float* out = (float*)d_out;

  // workspace (~78.4 MB): Q | cursor | bucket | ent0b | h1b | order | hist |
  // binCur (128 B-aligned)
  char* ws = (char*)d_ws;
  float*    Q      = (float*)ws;                              // 16384 B
  int*      cursor = (int*)(ws + 16384);                      // 800000 B
  unsigned* bucket = (unsigned*)(ws + 816384);                // 25.6 MB
  ushort*   ent0b  = (ushort*)(ws + 816384 + 25600000);       // 25.6 MB
  ushort*   h1b    = (ushort*)(ws + 816384 + 51200000);       // 25.6 MB
  unsigned* order  = (unsigned*)(ws + 816384 + 76800000);     // 800000 B
  int*      hist   = (int*)(ws + 816384 + 77600000);          // 132 B (pad 128)
  int*      binCur = (int*)(ws + 816384 + 77600128);          // 132 B

  // ---- preamble: prep (Q + bf16 table + zero cursor/hist) + bucket fill ----
  prep<<<(N_ENT * DIM / 4 + 255) / 256, 256, 0, stream>>>(
      W, rel, Q, (const float4*)ent0, (uint2*)ent0b, cursor, hist);
  fill_bucket<<<NCOLOR * NSLICE, 256, 0, stream>>>(
      (const int4*)head, (const int4*)tail, (const int4*)etype, cursor, bucket);

  // ---- degree-grouped schedule: counting sort of heads (33 bins) ----
  hist_deg<<<(N_ENT + 255) / 256, 256, 0, stream>>>(cursor, hist);
  scan_deg<<<1, 64, 0, stream>>>(hist, binCur);
  scatter_deg<<<(N_ENT + 255) / 256, 256, 0, stream>>>(cursor, binCur, order);

  // ---- hops: one persistent kernel each ----
  hop_kernel<1><<<2048, 256, 0, stream>>>(ent0, ent0b, (const float4*)Q,
                                          order, bucket, (uint2*)h1b, nullptr);
  hop_kernel<2><<<2048, 256, 0, stream>>>(ent0, h1b, (const float4*)Q,
                                          order, bucket, nullptr, out);
}